// Round 20
// baseline (116.493 us; speedup 1.0000x reference)
//
#include <hip/hip_runtime.h>

typedef float f32x4 __attribute__((ext_vector_type(4)));
typedef __bf16 bf16x8 __attribute__((ext_vector_type(8)));
typedef unsigned short u16;

__device__ __forceinline__ f32x4 mfma16(bf16x8 a, bf16x8 b, f32x4 c) {
  return __builtin_amdgcn_mfma_f32_16x16x32_bf16(a, b, c, 0, 0, 0);
}

__device__ __forceinline__ void gll16(const void* g, void* l) {
  __builtin_amdgcn_global_load_lds(
      (const __attribute__((address_space(1))) void*)g,
      (__attribute__((address_space(3))) void*)l, 16, 0, 0);
}

// ---------------- fused f32 -> bf16 convert (x, Wp, Wo -> contiguous ws) ----
__global__ void cvt3_kernel(const float* __restrict__ x,
                            const float* __restrict__ wp,
                            const float* __restrict__ wo,
                            __bf16* __restrict__ out) {
  int idx = blockIdx.x * blockDim.x + threadIdx.x;
  int stride = gridDim.x * blockDim.x;
  for (int i = idx; i < 1048576; i += stride) {
    const float* src;
    if (i < 524288) src = x + (size_t)i * 8;
    else if (i < 917504) src = wp + (size_t)(i - 524288) * 8;
    else src = wo + (size_t)(i - 917504) * 8;
    f32x4 a = *(const f32x4*)src;
    f32x4 b = *(const f32x4*)(src + 4);
    bf16x8 r;
#pragma unroll
    for (int j = 0; j < 4; ++j) {
      r[j] = (__bf16)a[j];
      r[4 + j] = (__bf16)b[j];
    }
    *(bf16x8*)(out + (size_t)i * 8) = r;
  }
}

// ---------------- bf16 GEMM: 3-deep counted-vmcnt + chunk swizzle ----------
// (session-best structure; K-loop phase rotation kept from r19 — neutral.
// LDS chunk16 i holds global chunk ((i&3)-(row>>1))&3 via pre-swizzled
// gll16 source; read slot ((lg+(lr>>1))&3) -> conflict-free ds_read_b128.
// Counted vmcnt keeps 2 tiles of loads in flight across barriers.)
// MODE 0: f32 out. MODE 1: QKV pack (Q row-major; K/V fragment-linear).
template <int BM, int BN, int MODE>
__global__ __launch_bounds__(256, 3) void gemm_bt(
    const u16* __restrict__ A, const u16* __restrict__ B,
    const float* __restrict__ bias, float* __restrict__ Cout,
    __bf16* __restrict__ qb, __bf16* __restrict__ kp, __bf16* __restrict__ vp,
    int M, int N, int K, int mtiles) {
  constexpr int MREP = BM / 32;
  constexpr int NREP = BN / 32;
  constexpr int LA = BM / 64;
  constexpr int LB = BN / 64;
  constexpr int LPT = LA + LB;
  static_assert(LPT == 4 || LPT == 3, "vmcnt literals cover LPT 3/4 only");
  __shared__ u16 lA[3 * BM * 32];
  __shared__ u16 lB[3 * BN * 32];
  const int tid = threadIdx.x;
  const int wid = tid >> 6;
  const int lane = tid & 63;
  const int lr = lane & 15;
  const int lg = lane >> 4;

  const int nwg = gridDim.x;
  const int lid = blockIdx.x;
  const int sw = (lid & 7) * (nwg >> 3) + (lid >> 3);
  const int bm = (sw % mtiles) * BM;
  const int bn = (sw / mtiles) * BN;
  const int wm = (wid >> 1) * (BM / 2);
  const int wn = (wid & 1) * (BN / 2);

  f32x4 acc[MREP][NREP] = {};

  auto stage = [&](int bf, int t) {
    const int kt = t * 32;
    char* baseA = (char*)lA + bf * (BM * 64);
    char* baseB = (char*)lB + bf * (BN * 64);
#pragma unroll
    for (int j = 0; j < LA; ++j) {
      int i16 = tid + j * 256;
      int row = i16 >> 2;
      int c = ((i16 & 3) - (row >> 1)) & 3;
      gll16(A + (size_t)(bm + row) * K + kt + c * 8, baseA + i16 * 16);
    }
#pragma unroll
    for (int j = 0; j < LB; ++j) {
      int i16 = tid + j * 256;
      int row = i16 >> 2;
      int c = ((i16 & 3) - (row >> 1)) & 3;
      gll16(B + (size_t)(bn + row) * K + kt + c * 8, baseB + i16 * 16);
    }
  };

  const int T = K / 32;
  const int tmask = T - 1;
  const int t0 = (sw * 7) & tmask;
  stage(0, t0);
  stage(1, (t0 + 1) & tmask);
  stage(2, (t0 + 2) & tmask);

  const int slotA = ((lg + (lr >> 1)) & 3) * 8;

  for (int i = 0; i < T; ++i) {
    const int rem = T - 1 - i;
    if (rem >= 2) {
      if constexpr (LPT == 4)
        asm volatile("s_waitcnt vmcnt(8)" ::: "memory");
      else
        asm volatile("s_waitcnt vmcnt(6)" ::: "memory");
    } else if (rem == 1) {
      if constexpr (LPT == 4)
        asm volatile("s_waitcnt vmcnt(4)" ::: "memory");
      else
        asm volatile("s_waitcnt vmcnt(3)" ::: "memory");
    } else {
      asm volatile("s_waitcnt vmcnt(0)" ::: "memory");
    }
    __builtin_amdgcn_s_barrier();

    const u16* cA = lA + (i % 3) * BM * 32;
    const u16* cB = lB + (i % 3) * BN * 32;
    bf16x8 af[MREP], bfr[NREP];
#pragma unroll
    for (int mt = 0; mt < MREP; ++mt)
      af[mt] = *(const bf16x8*)&cA[(wm + mt * 16 + lr) * 32 + slotA];
#pragma unroll
    for (int nt = 0; nt < NREP; ++nt)
      bfr[nt] = *(const bf16x8*)&cB[(wn + nt * 16 + lr) * 32 + slotA];
#pragma unroll
    for (int mt = 0; mt < MREP; ++mt)
#pragma unroll
      for (int nt = 0; nt < NREP; ++nt)
        acc[mt][nt] = mfma16(af[mt], bfr[nt], acc[mt][nt]);

    __builtin_amdgcn_sched_barrier(0);
    __builtin_amdgcn_s_barrier();
    if (i + 3 < T) stage(i % 3, (t0 + i + 3) & tmask);
  }

#pragma unroll
  for (int nt = 0; nt < NREP; ++nt) {
    int col = bn + wn + nt * 16 + lr;
    float bv = bias[col];
#pragma unroll
    for (int mt = 0; mt < MREP; ++mt) {
#pragma unroll
      for (int r = 0; r < 4; ++r) {
        int row = bm + wm + mt * 16 + lg * 4 + r;
        float val = acc[mt][nt][r] + bv;
        if (MODE == 0) {
          Cout[(size_t)row * N + col] = val;
        } else {
          __bf16 bx = (__bf16)val;
          int b = row >> 11, s = row & 2047;
          int third = col >> 10, hd = col & 1023;
          int h = hd >> 6, d = hd & 63;
          if (third == 0) {
            qb[(size_t)row * 1024 + hd] = bx;
          } else {
            int bh = b * 16 + h, t2 = s >> 6, sr = s & 63;
            size_t tb = ((size_t)(bh * 32 + t2)) * 4096;
            if (third == 1)
              kp[tb + (sr >> 4) * 1024 + (d >> 5) * 512 + ((d >> 3) & 3) * 128 +
                 (sr & 15) * 8 + (d & 7)] = bx;
            else
              vp[tb + (d >> 4) * 1024 + (sr >> 5) * 512 + ((sr >> 3) & 3) * 128 +
                 (d & 15) * 8 + (sr & 7)] = bx;
          }
        }
      }
    }
  }
}

// ---------------- fused causal+ALiBi flash attention (paired waves) -------
// 2048 blocks x 2 waves. Wave wid processes a16 = 2*pr + wid; ntl(2pr) ==
// ntl(2pr+1) exactly, so both waves run identical-length loops over the
// SAME K/V tiles in natural lockstep -> second wave's tile reads hit L1;
// L2 K/V traffic halves (was ~41 TB/s, above the 34.5 TB/s L2 ceiling).
// No barriers, no extra VGPR, same 4 waves/SIMD occupancy.
// Defer-max softmax (THR=8 log2); T5 setprio around MFMA clusters.
__global__ __launch_bounds__(128, 4) void attn_kernel(
    const __bf16* __restrict__ qb, const __bf16* __restrict__ kp,
    const __bf16* __restrict__ vp, __bf16* __restrict__ aout) {
  __shared__ __bf16 p_lds[2][16][72];
  const int wid = threadIdx.x >> 6;
  const int lane = threadIdx.x & 63;
  const int lr = lane & 15;
  const int lg = lane >> 4;

  const int lid = blockIdx.x;
  const int xcd = lid & 7;
  const int rest = lid >> 3;            // 0..255
  const int bh = xcd * 4 + (rest & 3);  // 4 bh per XCD (K/V 2 MB, L2-fit)
  const int pr = 63 - (rest >> 2);      // pair index, descending
  const int a16 = pr * 2 + wid;         // this wave's 16-row qtile
  const int b = bh >> 4, h = bh & 15;
  const int qr0 = a16 * 16;
  const int ntl = (a16 >> 2) + 1;       // identical for both waves of block

  const float LOG2E = 1.4426950408889634f;
  const float c1 = 0.125f * LOG2E;
  const float c2 = exp2f(-(float)(h + 1) * 0.5f) * LOG2E;

  bf16x8 ones;
#pragma unroll
  for (int j = 0; j < 8; ++j) ones[j] = (__bf16)1.0f;

  const u16* ktiles = (const u16*)kp + (size_t)bh * 32 * 4096;
  const u16* vtiles = (const u16*)vp + (size_t)bh * 32 * 4096;

  const __bf16* qrow = qb + (size_t)(b * 2048 + qr0 + lr) * 1024 + h * 64;
  bf16x8 qf0 = *(const bf16x8*)(qrow + lg * 8);
  bf16x8 qf1 = *(const bf16x8*)(qrow + 32 + lg * 8);

  float m[4], l[4], cq[4];
  f32x4 o[4];
#pragma unroll
  for (int r = 0; r < 4; ++r) {
    m[r] = 0.f;  // defer-max
    l[r] = 0.f;
    cq[r] = c2 * (float)(qr0 + lg * 4 + r);
  }
#pragma unroll
  for (int dt = 0; dt < 4; ++dt) o[dt] = (f32x4){0.f, 0.f, 0.f, 0.f};

  for (int t = 0; t < ntl; ++t) {
    const u16* kb = ktiles + (size_t)t * 4096;
    const u16* vb = vtiles + (size_t)t * 4096;
    const int kv = t * 64;
    const bool last = (t == ntl - 1);

    bf16x8 ka[8], va[8];
#pragma unroll
    for (int j = 0; j < 8; ++j)
      ka[j] = *(const bf16x8*)(kb + j * 512 + lane * 8);
#pragma unroll
    for (int j = 0; j < 8; ++j)
      va[j] = *(const bf16x8*)(vb + j * 512 + lane * 8);

    // ---- QK^T ----
    f32x4 s[4];
    __builtin_amdgcn_s_setprio(1);
#pragma unroll
    for (int nt = 0; nt < 4; ++nt) {
      f32x4 tt = (f32x4){0.f, 0.f, 0.f, 0.f};
      tt = mfma16(qf0, ka[nt * 2], tt);
      tt = mfma16(qf1, ka[nt * 2 + 1], tt);
      s[nt] = tt;
    }
    __builtin_amdgcn_s_setprio(0);

    // ---- logits (log2 domain) ----
#pragma unroll
    for (int nt = 0; nt < 4; ++nt) {
      float bnt = c2 * (float)(kv + nt * 16 + lr);
#pragma unroll
      for (int r = 0; r < 4; ++r)
        s[nt][r] = __builtin_fmaf(s[nt][r], c1, bnt - cq[r]);
    }
    if (last) {  // diagonal tile: causal mask
#pragma unroll
      for (int nt = 0; nt < 4; ++nt) {
        float kf = (float)(kv + nt * 16 + lr);
#pragma unroll
        for (int r = 0; r < 4; ++r) {
          float qi = (float)(qr0 + lg * 4 + r);
          if (kf > qi) s[nt][r] = -1e30f;
        }
      }
    }

    // ---- defer-max check (no cross-lane in common path) ----
    float pm[4];
#pragma unroll
    for (int r = 0; r < 4; ++r)
      pm[r] = fmaxf(fmaxf(s[0][r], s[1][r]), fmaxf(s[2][r], s[3][r]));
    bool ok = (pm[0] <= m[0] + 8.f) && (pm[1] <= m[1] + 8.f) &&
              (pm[2] <= m[2] + 8.f) && (pm[3] <= m[3] + 8.f);
    if (!__all(ok)) {  // rare: full reduce + rescale
#pragma unroll
      for (int r = 0; r < 4; ++r)
#pragma unroll
        for (int d = 1; d < 16; d <<= 1)
          pm[r] = fmaxf(pm[r], __shfl_xor(pm[r], d));
#pragma unroll
      for (int r = 0; r < 4; ++r) {
        float mn = fmaxf(m[r], pm[r]);
        float fac = __builtin_amdgcn_exp2f(m[r] - mn);
        m[r] = mn;
        l[r] *= fac;
#pragma unroll
        for (int dt = 0; dt < 4; ++dt) o[dt][r] *= fac;
      }
    }

    // ---- P = exp2(s - m) -> wave-private LDS ----
#pragma unroll
    for (int nt = 0; nt < 4; ++nt)
#pragma unroll
      for (int r = 0; r < 4; ++r) {
        float e = __builtin_amdgcn_exp2f(s[nt][r] - m[r]);
        p_lds[wid][lg * 4 + r][nt * 16 + lr] = (__bf16)e;
      }

    bf16x8 pa0 = *(const bf16x8*)&p_lds[wid][lr][lg * 8];
    bf16x8 pa1 = *(const bf16x8*)&p_lds[wid][lr][32 + lg * 8];

    // ---- row-sum via ones-MFMA + PV ----
    __builtin_amdgcn_s_setprio(1);
    {
      f32x4 tt = (f32x4){0.f, 0.f, 0.f, 0.f};
      tt = mfma16(pa0, ones, tt);
      tt = mfma16(pa1, ones, tt);
#pragma unroll
      for (int r = 0; r < 4; ++r) l[r] += tt[r];
    }
#pragma unroll
    for (int dt = 0; dt < 4; ++dt) {
      o[dt] = mfma16(pa0, va[dt * 2], o[dt]);
      o[dt] = mfma16(pa1, va[dt * 2 + 1], o[dt]);
    }
    __builtin_amdgcn_s_setprio(0);
  }

  // ---- epilogue (row-major bf16) ----
#pragma unroll
  for (int dt = 0; dt < 4; ++dt)
#pragma unroll
    for (int r = 0; r < 4; ++r) {
      float val = o[dt][r] / l[r];
      aout[(size_t)(b * 2048 + qr0 + lg * 4 + r) * 1024 + h * 64 + dt * 16 + lr] =
          (__bf16)val;
    }
}

extern "C" void kernel_launch(void* const* d_in, const int* in_sizes, int n_in,
                              void* d_out, int out_size, void* d_ws, size_t ws_size,
                              hipStream_t stream) {
  (void)in_sizes; (void)n_in; (void)out_size; (void)ws_size;
  const float* x = (const float*)d_in[0];
  const float* Wp = (const float*)d_in[1];
  const float* bp = (const float*)d_in[2];
  const float* Wo = (const float*)d_in[3];
  const float* bo = (const float*)d_in[4];
  float* out = (float*)d_out;

  char* ws = (char*)d_ws;
  u16* xb  = (u16*)(ws);                        // 8 MB  x bf16 row-major
  u16* wpb = (u16*)(ws + (size_t)(8u << 20));   // 6 MB  Wp bf16 row-major
  u16* wob = (u16*)(ws + (size_t)(14u << 20));  // 2 MB  Wo bf16 row-major
  u16* qbp = (u16*)(ws + (size_t)(16u << 20));  // 8 MB  Q row-major
  u16* kpp = (u16*)(ws + (size_t)(24u << 20));  // 8 MB  K fragment tiles
  u16* vpp = (u16*)(ws + (size_t)(32u << 20));  // 8 MB  V fragment tiles
  u16* ab  = xb;  // attention output reuses x_bf16 space

  cvt3_kernel<<<2048, 256, 0, stream>>>(x, Wp, Wo, (__bf16*)xb);
  // gemm1: 3-deep pipelined 128x128 + swizzle (session-best), grid 768
  gemm_bt<128, 128, 1><<<768, 256, 0, stream>>>(
      xb, wpb, bp, nullptr, (__bf16*)qbp, (__bf16*)kpp, (__bf16*)vpp,
      4096, 3072, 1024, 32);
  // attn: paired-wave blocks (2 waves share K/V tiles via L1), 2048 blocks
  attn_kernel<<<2048, 128, 0, stream>>>(
      (const __bf16*)qbp, (const __bf16*)kpp, (const __bf16*)vpp, (__bf16*)ab);
  // gemm2: 3-deep pipelined 128x64, grid 512 (2/CU)
  gemm_bt<128, 64, 0><<<512, 256, 0, stream>>>(
      ab, wob, bo, out, nullptr, nullptr, nullptr, 4096, 1024, 1024, 32);
}

// Round 21
// 113.242 us; speedup vs baseline: 1.0287x; 1.0287x over previous
//
#include <hip/hip_runtime.h>

typedef float f32x4 __attribute__((ext_vector_type(4)));
typedef __bf16 bf16x8 __attribute__((ext_vector_type(8)));
typedef unsigned short u16;

__device__ __forceinline__ f32x4 mfma16(bf16x8 a, bf16x8 b, f32x4 c) {
  return __builtin_amdgcn_mfma_f32_16x16x32_bf16(a, b, c, 0, 0, 0);
}

__device__ __forceinline__ void gll16(const void* g, void* l) {
  __builtin_amdgcn_global_load_lds(
      (const __attribute__((address_space(1))) void*)g,
      (__attribute__((address_space(3))) void*)l, 16, 0, 0);
}

// ---------------- fused f32 -> bf16 convert (x, Wp, Wo -> contiguous ws) ----
__global__ void cvt3_kernel(const float* __restrict__ x,
                            const float* __restrict__ wp,
                            const float* __restrict__ wo,
                            __bf16* __restrict__ out) {
  int idx = blockIdx.x * blockDim.x + threadIdx.x;
  int stride = gridDim.x * blockDim.x;
  for (int i = idx; i < 1048576; i += stride) {
    const float* src;
    if (i < 524288) src = x + (size_t)i * 8;
    else if (i < 917504) src = wp + (size_t)(i - 524288) * 8;
    else src = wo + (size_t)(i - 917504) * 8;
    f32x4 a = *(const f32x4*)src;
    f32x4 b = *(const f32x4*)(src + 4);
    bf16x8 r;
#pragma unroll
    for (int j = 0; j < 4; ++j) {
      r[j] = (__bf16)a[j];
      r[4 + j] = (__bf16)b[j];
    }
    *(bf16x8*)(out + (size_t)i * 8) = r;
  }
}

// ---------------- bf16 GEMM: 3-deep counted-vmcnt + chunk swizzle ----------
// (session-best structure + K-loop phase rotation (neutral, kept).
// LDS chunk16 i holds global chunk ((i&3)-(row>>1))&3 via pre-swizzled
// gll16 source; read slot ((lg+(lr>>1))&3) -> conflict-free ds_read_b128.
// Counted vmcnt keeps 2 tiles of loads in flight across barriers.)
// MODE 0: f32 out. MODE 1: QKV pack (Q row-major; K/V fragment-linear).
template <int BM, int BN, int MODE>
__global__ __launch_bounds__(256, 3) void gemm_bt(
    const u16* __restrict__ A, const u16* __restrict__ B,
    const float* __restrict__ bias, float* __restrict__ Cout,
    __bf16* __restrict__ qb, __bf16* __restrict__ kp, __bf16* __restrict__ vp,
    int M, int N, int K, int mtiles) {
  constexpr int MREP = BM / 32;
  constexpr int NREP = BN / 32;
  constexpr int LA = BM / 64;
  constexpr int LB = BN / 64;
  constexpr int LPT = LA + LB;
  static_assert(LPT == 4 || LPT == 3, "vmcnt literals cover LPT 3/4 only");
  __shared__ u16 lA[3 * BM * 32];
  __shared__ u16 lB[3 * BN * 32];
  const int tid = threadIdx.x;
  const int wid = tid >> 6;
  const int lane = tid & 63;
  const int lr = lane & 15;
  const int lg = lane >> 4;

  const int nwg = gridDim.x;
  const int lid = blockIdx.x;
  const int sw = (lid & 7) * (nwg >> 3) + (lid >> 3);
  const int bm = (sw % mtiles) * BM;
  const int bn = (sw / mtiles) * BN;
  const int wm = (wid >> 1) * (BM / 2);
  const int wn = (wid & 1) * (BN / 2);

  f32x4 acc[MREP][NREP] = {};

  auto stage = [&](int bf, int t) {
    const int kt = t * 32;
    char* baseA = (char*)lA + bf * (BM * 64);
    char* baseB = (char*)lB + bf * (BN * 64);
#pragma unroll
    for (int j = 0; j < LA; ++j) {
      int i16 = tid + j * 256;
      int row = i16 >> 2;
      int c = ((i16 & 3) - (row >> 1)) & 3;
      gll16(A + (size_t)(bm + row) * K + kt + c * 8, baseA + i16 * 16);
    }
#pragma unroll
    for (int j = 0; j < LB; ++j) {
      int i16 = tid + j * 256;
      int row = i16 >> 2;
      int c = ((i16 & 3) - (row >> 1)) & 3;
      gll16(B + (size_t)(bn + row) * K + kt + c * 8, baseB + i16 * 16);
    }
  };

  const int T = K / 32;
  const int tmask = T - 1;
  const int t0 = (sw * 7) & tmask;
  stage(0, t0);
  stage(1, (t0 + 1) & tmask);
  stage(2, (t0 + 2) & tmask);

  const int slotA = ((lg + (lr >> 1)) & 3) * 8;

  for (int i = 0; i < T; ++i) {
    const int rem = T - 1 - i;
    if (rem >= 2) {
      if constexpr (LPT == 4)
        asm volatile("s_waitcnt vmcnt(8)" ::: "memory");
      else
        asm volatile("s_waitcnt vmcnt(6)" ::: "memory");
    } else if (rem == 1) {
      if constexpr (LPT == 4)
        asm volatile("s_waitcnt vmcnt(4)" ::: "memory");
      else
        asm volatile("s_waitcnt vmcnt(3)" ::: "memory");
    } else {
      asm volatile("s_waitcnt vmcnt(0)" ::: "memory");
    }
    __builtin_amdgcn_s_barrier();

    const u16* cA = lA + (i % 3) * BM * 32;
    const u16* cB = lB + (i % 3) * BN * 32;
    bf16x8 af[MREP], bfr[NREP];
#pragma unroll
    for (int mt = 0; mt < MREP; ++mt)
      af[mt] = *(const bf16x8*)&cA[(wm + mt * 16 + lr) * 32 + slotA];
#pragma unroll
    for (int nt = 0; nt < NREP; ++nt)
      bfr[nt] = *(const bf16x8*)&cB[(wn + nt * 16 + lr) * 32 + slotA];
#pragma unroll
    for (int mt = 0; mt < MREP; ++mt)
#pragma unroll
      for (int nt = 0; nt < NREP; ++nt)
        acc[mt][nt] = mfma16(af[mt], bfr[nt], acc[mt][nt]);

    __builtin_amdgcn_sched_barrier(0);
    __builtin_amdgcn_s_barrier();
    if (i + 3 < T) stage(i % 3, (t0 + i + 3) & tmask);
  }

#pragma unroll
  for (int nt = 0; nt < NREP; ++nt) {
    int col = bn + wn + nt * 16 + lr;
    float bv = bias[col];
#pragma unroll
    for (int mt = 0; mt < MREP; ++mt) {
#pragma unroll
      for (int r = 0; r < 4; ++r) {
        int row = bm + wm + mt * 16 + lg * 4 + r;
        float val = acc[mt][nt][r] + bv;
        if (MODE == 0) {
          Cout[(size_t)row * N + col] = val;
        } else {
          __bf16 bx = (__bf16)val;
          int b = row >> 11, s = row & 2047;
          int third = col >> 10, hd = col & 1023;
          int h = hd >> 6, d = hd & 63;
          if (third == 0) {
            qb[(size_t)row * 1024 + hd] = bx;
          } else {
            int bh = b * 16 + h, t2 = s >> 6, sr = s & 63;
            size_t tb = ((size_t)(bh * 32 + t2)) * 4096;
            if (third == 1)
              kp[tb + (sr >> 4) * 1024 + (d >> 5) * 512 + ((d >> 3) & 3) * 128 +
                 (sr & 15) * 8 + (d & 7)] = bx;
            else
              vp[tb + (d >> 4) * 1024 + (sr >> 5) * 512 + ((sr >> 3) & 3) * 128 +
                 (d & 15) * 8 + (sr & 7)] = bx;
          }
        }
      }
    }
  }
}

// ---------------- fused causal+ALiBi flash attention (16-row waves) -------
// 4096 independent 1-wave blocks (32 bh x 128 a16-tiles, descending):
// 4 waves/SIMD TLP (VGPR ~60 -> no occupancy cliff). K/V fragment-linear
// packed tiles in L2 (contiguous 1 KB fragment loads). Defer-max softmax
// (THR=8 log2); T5 setprio around MFMA clusters (+4-7% this regime, m191).
__global__ __launch_bounds__(64, 4) void attn_kernel(
    const __bf16* __restrict__ qb, const __bf16* __restrict__ kp,
    const __bf16* __restrict__ vp, __bf16* __restrict__ aout) {
  __shared__ __bf16 p_lds[16][72];
  const int lane = threadIdx.x & 63;
  const int lr = lane & 15;
  const int lg = lane >> 4;

  const int lid = blockIdx.x;
  const int xcd = lid & 7;
  const int rest = lid >> 3;
  const int bh = xcd * 4 + (rest & 3);  // 4 bh per XCD (K/V 2 MB, L2-fit)
  const int a16 = 127 - (rest >> 2);    // descending: big blocks first
  const int b = bh >> 4, h = bh & 15;
  const int qr0 = a16 * 16;
  const int ntl = (a16 >> 2) + 1;

  const float LOG2E = 1.4426950408889634f;
  const float c1 = 0.125f * LOG2E;
  const float c2 = exp2f(-(float)(h + 1) * 0.5f) * LOG2E;

  bf16x8 ones;
#pragma unroll
  for (int j = 0; j < 8; ++j) ones[j] = (__bf16)1.0f;

  const u16* ktiles = (const u16*)kp + (size_t)bh * 32 * 4096;
  const u16* vtiles = (const u16*)vp + (size_t)bh * 32 * 4096;

  const __bf16* qrow = qb + (size_t)(b * 2048 + qr0 + lr) * 1024 + h * 64;
  bf16x8 qf0 = *(const bf16x8*)(qrow + lg * 8);
  bf16x8 qf1 = *(const bf16x8*)(qrow + 32 + lg * 8);

  float m[4], l[4], cq[4];
  f32x4 o[4];
#pragma unroll
  for (int r = 0; r < 4; ++r) {
    m[r] = 0.f;  // defer-max
    l[r] = 0.f;
    cq[r] = c2 * (float)(qr0 + lg * 4 + r);
  }
#pragma unroll
  for (int dt = 0; dt < 4; ++dt) o[dt] = (f32x4){0.f, 0.f, 0.f, 0.f};

  for (int t = 0; t < ntl; ++t) {
    const u16* kb = ktiles + (size_t)t * 4096;
    const u16* vb = vtiles + (size_t)t * 4096;
    const int kv = t * 64;
    const bool last = (t == ntl - 1);

    bf16x8 ka[8], va[8];
#pragma unroll
    for (int j = 0; j < 8; ++j)
      ka[j] = *(const bf16x8*)(kb + j * 512 + lane * 8);
#pragma unroll
    for (int j = 0; j < 8; ++j)
      va[j] = *(const bf16x8*)(vb + j * 512 + lane * 8);

    // ---- QK^T ----
    f32x4 s[4];
    __builtin_amdgcn_s_setprio(1);
#pragma unroll
    for (int nt = 0; nt < 4; ++nt) {
      f32x4 tt = (f32x4){0.f, 0.f, 0.f, 0.f};
      tt = mfma16(qf0, ka[nt * 2], tt);
      tt = mfma16(qf1, ka[nt * 2 + 1], tt);
      s[nt] = tt;
    }
    __builtin_amdgcn_s_setprio(0);

    // ---- logits (log2 domain) ----
#pragma unroll
    for (int nt = 0; nt < 4; ++nt) {
      float bnt = c2 * (float)(kv + nt * 16 + lr);
#pragma unroll
      for (int r = 0; r < 4; ++r)
        s[nt][r] = __builtin_fmaf(s[nt][r], c1, bnt - cq[r]);
    }
    if (last) {  // diagonal tile: causal mask
#pragma unroll
      for (int nt = 0; nt < 4; ++nt) {
        float kf = (float)(kv + nt * 16 + lr);
#pragma unroll
        for (int r = 0; r < 4; ++r) {
          float qi = (float)(qr0 + lg * 4 + r);
          if (kf > qi) s[nt][r] = -1e30f;
        }
      }
    }

    // ---- defer-max check (no cross-lane in common path) ----
    float pm[4];
#pragma unroll
    for (int r = 0; r < 4; ++r)
      pm[r] = fmaxf(fmaxf(s[0][r], s[1][r]), fmaxf(s[2][r], s[3][r]));
    bool ok = (pm[0] <= m[0] + 8.f) && (pm[1] <= m[1] + 8.f) &&
              (pm[2] <= m[2] + 8.f) && (pm[3] <= m[3] + 8.f);
    if (!__all(ok)) {  // rare: full reduce + rescale
#pragma unroll
      for (int r = 0; r < 4; ++r)
#pragma unroll
        for (int d = 1; d < 16; d <<= 1)
          pm[r] = fmaxf(pm[r], __shfl_xor(pm[r], d));
#pragma unroll
      for (int r = 0; r < 4; ++r) {
        float mn = fmaxf(m[r], pm[r]);
        float fac = __builtin_amdgcn_exp2f(m[r] - mn);
        m[r] = mn;
        l[r] *= fac;
#pragma unroll
        for (int dt = 0; dt < 4; ++dt) o[dt][r] *= fac;
      }
    }

    // ---- P = exp2(s - m) -> wave-private LDS ----
#pragma unroll
    for (int nt = 0; nt < 4; ++nt)
#pragma unroll
      for (int r = 0; r < 4; ++r) {
        float e = __builtin_amdgcn_exp2f(s[nt][r] - m[r]);
        p_lds[lg * 4 + r][nt * 16 + lr] = (__bf16)e;
      }

    bf16x8 pa0 = *(const bf16x8*)&p_lds[lr][lg * 8];
    bf16x8 pa1 = *(const bf16x8*)&p_lds[lr][32 + lg * 8];

    // ---- row-sum via ones-MFMA + PV ----
    __builtin_amdgcn_s_setprio(1);
    {
      f32x4 tt = (f32x4){0.f, 0.f, 0.f, 0.f};
      tt = mfma16(pa0, ones, tt);
      tt = mfma16(pa1, ones, tt);
#pragma unroll
      for (int r = 0; r < 4; ++r) l[r] += tt[r];
    }
#pragma unroll
    for (int dt = 0; dt < 4; ++dt) {
      o[dt] = mfma16(pa0, va[dt * 2], o[dt]);
      o[dt] = mfma16(pa1, va[dt * 2 + 1], o[dt]);
    }
    __builtin_amdgcn_s_setprio(0);
  }

  // ---- epilogue (row-major bf16) ----
#pragma unroll
  for (int dt = 0; dt < 4; ++dt)
#pragma unroll
    for (int r = 0; r < 4; ++r) {
      float val = o[dt][r] / l[r];
      aout[(size_t)(b * 2048 + qr0 + lg * 4 + r) * 1024 + h * 64 + dt * 16 + lr] =
          (__bf16)val;
    }
}

extern "C" void kernel_launch(void* const* d_in, const int* in_sizes, int n_in,
                              void* d_out, int out_size, void* d_ws, size_t ws_size,
                              hipStream_t stream) {
  (void)in_sizes; (void)n_in; (void)out_size; (void)ws_size;
  const float* x = (const float*)d_in[0];
  const float* Wp = (const float*)d_in[1];
  const float* bp = (const float*)d_in[2];
  const float* Wo = (const float*)d_in[3];
  const float* bo = (const float*)d_in[4];
  float* out = (float*)d_out;

  char* ws = (char*)d_ws;
  u16* xb  = (u16*)(ws);                        // 8 MB  x bf16 row-major
  u16* wpb = (u16*)(ws + (size_t)(8u << 20));   // 6 MB  Wp bf16 row-major
  u16* wob = (u16*)(ws + (size_t)(14u << 20));  // 2 MB  Wo bf16 row-major
  u16* qbp = (u16*)(ws + (size_t)(16u << 20));  // 8 MB  Q row-major
  u16* kpp = (u16*)(ws + (size_t)(24u << 20));  // 8 MB  K fragment tiles
  u16* vpp = (u16*)(ws + (size_t)(32u << 20));  // 8 MB  V fragment tiles
  u16* ab  = xb;  // attention output reuses x_bf16 space

  cvt3_kernel<<<2048, 256, 0, stream>>>(x, Wp, Wo, (__bf16*)xb);
  // gemm1: 3-deep pipelined 128x128 + swizzle + K-phase rotation, grid 768
  gemm_bt<128, 128, 1><<<768, 256, 0, stream>>>(
      xb, wpb, bp, nullptr, (__bf16*)qbp, (__bf16*)kpp, (__bf16*)vpp,
      4096, 3072, 1024, 32);
  // attn: 16-row waves, 4096 one-wave blocks (4 waves/SIMD TLP)
  attn_kernel<<<4096, 64, 0, stream>>>(
      (const __bf16*)qbp, (const __bf16*)kpp, (const __bf16*)vpp, (__bf16*)ab);
  // gemm2: 3-deep pipelined 128x64 + K-phase rotation, grid 512 (2/CU)
  gemm_bt<128, 64, 0><<<512, 256, 0, stream>>>(
      ab, wob, bo, out, nullptr, nullptr, nullptr, 4096, 1024, 1024, 32);
}